// Round 1
// baseline (288.722 us; speedup 1.0000x reference)
//
#include <hip/hip_runtime.h>
#include <math.h>

#define KK 256
#define NN 65536
#define TT 64    // time-tile columns per block
#define WW 48    // scan lookback window; decay<=e^-1 -> tail error ~1e-21
#define TPAD 264 // 256 + 8 bf16 pad: breaks 512B-stride bank aliasing, keeps 16B align

typedef __bf16 bf16x8 __attribute__((ext_vector_type(8)));
typedef float f32x4 __attribute__((ext_vector_type(4)));

// ---------------------------------------------------------------------------
// Kernel 1: partial row sums of obs. Block b: row r=b>>3, eighth e=b&7.
// ---------------------------------------------------------------------------
__global__ __launch_bounds__(256) void rowsum_kernel(const float* __restrict__ obs,
                                                     float* __restrict__ partial) {
  const int b = blockIdx.x;
  const int r = b >> 3, e = b & 7;
  const int tid = threadIdx.x;
  const float4* p = (const float4*)(obs + (size_t)r * NN + e * 8192) + tid;
  float s = 0.f;
#pragma unroll
  for (int i = 0; i < 8; ++i) {
    float4 v = p[i * 256];
    s += (v.x + v.y) + (v.z + v.w);
  }
  __shared__ float red[256];
  red[tid] = s;
  __syncthreads();
  for (int off = 128; off > 0; off >>= 1) {
    if (tid < off) red[tid] += red[tid + off];
    __syncthreads();
  }
  if (tid == 0) partial[b] = red[0];
}

// ---------------------------------------------------------------------------
// Kernel 2: finalize mu0, convert Alpha -> bf16.
// ---------------------------------------------------------------------------
__global__ __launch_bounds__(256) void prep_kernel(const float* __restrict__ Alpha,
                                                   const float* __restrict__ partial,
                                                   float* __restrict__ mu0,
                                                   __bf16* __restrict__ AlphaB) {
  const int j = blockIdx.x;
  const int tid = threadIdx.x;
  AlphaB[(size_t)j * KK + tid] = (__bf16)Alpha[(size_t)j * KK + tid];
  if (tid == 0) {
    float s = 0.f;
#pragma unroll
    for (int i = 0; i < 8; ++i) s += partial[j * 8 + i];
    mu0[j] = s * (1.0f / NN) * 0.1f + 0.01f;
  }
}

// ---------------------------------------------------------------------------
// Kernel 3: fused windowed-scan + bf16-MFMA GEMM + softplus + lams0/lams1 +
//           loglik partial. Block b covers t in [b*TT, b*TT+TT).
//   MFMA operand order SWAPPED vs v0: D = S^T * Alpha^T = (Alpha*S)^T, so
//   D rows = t -> each lane's 4 acc regs are 4 CONSECUTIVE t for one j
//   -> float4 epilogue loads/stores. No atomics: per-block partial to ws.
// ---------------------------------------------------------------------------
__global__ __launch_bounds__(256, 2) void main_kernel(const float* __restrict__ obs,
                                                      const float* __restrict__ Beta,
                                                      const float* __restrict__ mu0,
                                                      const __bf16* __restrict__ AlphaB,
                                                      float* __restrict__ out,
                                                      float* __restrict__ bpart) {
  __shared__ __bf16 Slds[TT][TPAD];  // 33.8 KB
  const int tid = threadIdx.x;
  const int t0 = blockIdx.x * TT;

  // ---- scan phase: thread k computes S[k, t0..t0+63] via WW-step window ----
  {
    const int k = tid;
    const float beta = Beta[k];
    const float decay = expf(-beta);
    const float* row = obs + (size_t)k * NN;
    float g = 0.f;  // ~ G[k, t0-WW]; tail < e^-48
    if (t0 > 0) {
      const float4* p = (const float4*)(row + t0 - WW);
#pragma unroll
      for (int i = 0; i < WW / 4; ++i) {
        float4 v = p[i];
        g = decay * (g + v.x);
        g = decay * (g + v.y);
        g = decay * (g + v.z);
        g = decay * (g + v.w);
      }
    }
    Slds[0][k] = (__bf16)(beta * g);
    const float4* q = (const float4*)(row + t0);
#pragma unroll
    for (int i = 0; i < 15; ++i) {
      float4 v = q[i];
      g = decay * (g + v.x); Slds[4 * i + 1][k] = (__bf16)(beta * g);
      g = decay * (g + v.y); Slds[4 * i + 2][k] = (__bf16)(beta * g);
      g = decay * (g + v.z); Slds[4 * i + 3][k] = (__bf16)(beta * g);
      g = decay * (g + v.w); Slds[4 * i + 4][k] = (__bf16)(beta * g);
    }
    {  // tail: obs t0+60..62 -> S[61..63]
      float4 v = q[15];
      g = decay * (g + v.x); Slds[61][k] = (__bf16)(beta * g);
      g = decay * (g + v.y); Slds[62][k] = (__bf16)(beta * g);
      g = decay * (g + v.z); Slds[63][k] = (__bf16)(beta * g);
    }
  }
  __syncthreads();

  // ---- MFMA GEMM: wave w covers j in [64w, 64w+64), all 64 t ----
  const int wave = tid >> 6;
  const int lane = tid & 63;
  const int lquad = lane >> 4;  // k-octet selector / t-sub in D rows
  const int l16 = lane & 15;

  f32x4 acc[4][4];  // [ts][js]; acc[ts][js][r] = C^T[t0+ts*16+lquad*4+r][wave*64+js*16+l16]
#pragma unroll
  for (int a = 0; a < 4; ++a)
#pragma unroll
    for (int b = 0; b < 4; ++b) acc[a][b] = (f32x4){0.f, 0.f, 0.f, 0.f};

  const __bf16* Abase = AlphaB + (size_t)(wave * 64 + l16) * KK + lquad * 8;
  for (int k0 = 0; k0 < KK; k0 += 32) {
    bf16x8 afrag[4], sfrag[4];
#pragma unroll
    for (int js = 0; js < 4; ++js)
      afrag[js] = *(const bf16x8*)(Abase + (size_t)js * 16 * KK + k0);
#pragma unroll
    for (int ts = 0; ts < 4; ++ts)
      sfrag[ts] = *(const bf16x8*)&Slds[ts * 16 + l16][k0 + lquad * 8];
#pragma unroll
    for (int ts = 0; ts < 4; ++ts)
#pragma unroll
      for (int js = 0; js < 4; ++js)
        acc[ts][js] = __builtin_amdgcn_mfma_f32_16x16x32_bf16(
            sfrag[ts], afrag[js], acc[ts][js], 0, 0, 0);
  }

  // ---- epilogue: softplus, float4 lams0/lams1 stores, loglik partial ----
  float partial = 0.f;
  float* lams0 = out + 1;                       // 4B-aligned base (out+1)!
  float* lams1 = out + 1 + (size_t)KK * NN;
  float mj[4];
#pragma unroll
  for (int js = 0; js < 4; ++js) mj[js] = mu0[wave * 64 + js * 16 + l16];

#pragma unroll
  for (int ts = 0; ts < 4; ++ts) {
    const int tb = t0 + ts * 16 + lquad * 4;    // 4 consecutive t per lane
#pragma unroll
    for (int js = 0; js < 4; ++js) {
      const int j = wave * 64 + js * 16 + l16;
      const size_t off = (size_t)j * NN + tb;
      f32x4 v = acc[ts][js];
      f32x4 lam;
#pragma unroll
      for (int r = 0; r < 4; ++r) {
        const float x = v[r];                        // x >= 0 always
        lam[r] = x + __logf(1.f + __expf(-x));       // stable softplus
      }
      if (tb == 0) lam[0] = 0.f;                     // lams1[:,0] = 0
      const float m = mj[js];
      f32x4 mv = {m, m, m, m};
      // dest only 4B-aligned (out+1): memcpy lets compiler emit dwordx4
      __builtin_memcpy(lams1 + off, &lam, sizeof(lam));
      __builtin_memcpy(lams0 + off, &mv, sizeof(mv));
      const f32x4 o = *(const f32x4*)(obs + off);    // obs 16B-aligned
#pragma unroll
      for (int r = 0; r < 4; ++r)
        partial += o[r] * __logf(m + lam[r] + 1e-5f) - m - lam[r];
    }
  }

  // wave reduce, then block reduce through LDS (reused), NO atomics
#pragma unroll
  for (int off = 32; off > 0; off >>= 1)
    partial += __shfl_down(partial, off, 64);
  __syncthreads();                       // all waves done reading Slds
  float* red = (float*)&Slds[0][0];
  if (lane == 0) red[wave] = partial;
  __syncthreads();
  if (tid == 0) bpart[blockIdx.x] = (red[0] + red[1]) + (red[2] + red[3]);
}

// ---------------------------------------------------------------------------
// Kernel 4: sum 1024 per-block partials -> out[0]. One block.
// ---------------------------------------------------------------------------
__global__ __launch_bounds__(256) void finish_kernel(const float* __restrict__ bpart,
                                                     float* __restrict__ out) {
  const int tid = threadIdx.x;
  f32x4 v = ((const f32x4*)bpart)[tid];
  float s = (v[0] + v[1]) + (v[2] + v[3]);
#pragma unroll
  for (int off = 32; off > 0; off >>= 1)
    s += __shfl_down(s, off, 64);
  __shared__ float red[4];
  if ((tid & 63) == 0) red[tid >> 6] = s;
  __syncthreads();
  if (tid == 0) out[0] = (red[0] + red[1]) + (red[2] + red[3]);
}

// ---------------------------------------------------------------------------
extern "C" void kernel_launch(void* const* d_in, const int* in_sizes, int n_in,
                              void* d_out, int out_size, void* d_ws, size_t ws_size,
                              hipStream_t stream) {
  const float* obs   = (const float*)d_in[0];
  const float* Beta  = (const float*)d_in[1];
  const float* Alpha = (const float*)d_in[2];
  float* out = (float*)d_out;

  float* partial = (float*)d_ws;            // 2048 floats
  float* mu0 = partial + 2048;              // 256 floats
  __bf16* AlphaB = (__bf16*)(mu0 + 256);    // 65536 bf16 = 32768 floats
  float* bpart = (float*)(AlphaB + (size_t)KK * KK);  // 1024 floats

  hipLaunchKernelGGL(rowsum_kernel, dim3(KK * 8), dim3(256), 0, stream, obs, partial);
  hipLaunchKernelGGL(prep_kernel, dim3(KK), dim3(256), 0, stream, Alpha, partial,
                     mu0, AlphaB);
  hipLaunchKernelGGL(main_kernel, dim3(NN / TT), dim3(256), 0, stream,
                     obs, Beta, mu0, AlphaB, out, bpart);
  hipLaunchKernelGGL(finish_kernel, dim3(1), dim3(256), 0, stream, bpart, out);
}

// Round 2
// 243.671 us; speedup vs baseline: 1.1849x; 1.1849x over previous
//
#include <hip/hip_runtime.h>
#include <math.h>

#define KK 256
#define NN 65536
#define TT 64    // time-tile columns per block
#define WW 16    // scan lookback; decay<=e^-1 -> tail rel err ~e^-16=1e-7 << bf16 eps
#define TPAD 264 // 256 + 8 bf16 pad: breaks 512B-stride bank aliasing, keeps 16B align

typedef __bf16 bf16x8 __attribute__((ext_vector_type(8)));
typedef float f32x4 __attribute__((ext_vector_type(4)));

// ---------------------------------------------------------------------------
// Kernel 1: fused row-mean + mu0 finalize + Alpha->bf16. Block j owns row j.
//   obs row j: 65536 floats = 256 threads x 64 float4, coalesced.
// ---------------------------------------------------------------------------
__global__ __launch_bounds__(256) void prep_kernel(const float* __restrict__ obs,
                                                   const float* __restrict__ Alpha,
                                                   float* __restrict__ mu0,
                                                   __bf16* __restrict__ AlphaB) {
  const int j = blockIdx.x;
  const int tid = threadIdx.x;
  AlphaB[(size_t)j * KK + tid] = (__bf16)Alpha[(size_t)j * KK + tid];
  const float4* p = (const float4*)(obs + (size_t)j * NN) + tid;
  float s = 0.f;
#pragma unroll
  for (int i = 0; i < 64; ++i) {
    float4 v = p[i * 256];
    s += (v.x + v.y) + (v.z + v.w);
  }
  __shared__ float red[256];
  red[tid] = s;
  __syncthreads();
  for (int off = 128; off > 0; off >>= 1) {
    if (tid < off) red[tid] += red[tid + off];
    __syncthreads();
  }
  if (tid == 0) mu0[j] = red[0] * (1.0f / NN) * 0.1f + 0.01f;
}

// ---------------------------------------------------------------------------
// Kernel 2: fused windowed-scan + bf16-MFMA GEMM + softplus + lams0/lams1 +
//           loglik partial. XCD-swizzled: tile tb = (bid&7)*128 + bid>>3 so
//           each XCD's 128 co-resident blocks cover a CONTIGUOUS 8192-column
//           span -> L2 write-combines adjacent 256B/row runs into long
//           sequential HBM streams (HBM row-buffer locality).
// ---------------------------------------------------------------------------
__global__ __launch_bounds__(256, 2) void main_kernel(const float* __restrict__ obs,
                                                      const float* __restrict__ Beta,
                                                      const float* __restrict__ mu0,
                                                      const __bf16* __restrict__ AlphaB,
                                                      float* __restrict__ out,
                                                      float* __restrict__ bpart) {
  __shared__ __bf16 Slds[TT][TPAD];  // 33.8 KB
  const int tid = threadIdx.x;
  const int bid = blockIdx.x;
  const int tb = ((bid & 7) << 7) | (bid >> 3);  // bijective XCD swizzle (1024%8==0)
  const int t0 = tb * TT;

  // ---- scan phase: thread k computes S[k, t0..t0+63] via WW-step window ----
  {
    const int k = tid;
    const float beta = Beta[k];
    const float decay = expf(-beta);
    const float* row = obs + (size_t)k * NN;
    float g = 0.f;  // ~ G[k, t0-WW]; tail rel err < e^-16
    if (t0 > 0) {
      const float4* p = (const float4*)(row + t0 - WW);
#pragma unroll
      for (int i = 0; i < WW / 4; ++i) {
        float4 v = p[i];
        g = decay * (g + v.x);
        g = decay * (g + v.y);
        g = decay * (g + v.z);
        g = decay * (g + v.w);
      }
    }
    Slds[0][k] = (__bf16)(beta * g);
    const float4* q = (const float4*)(row + t0);
#pragma unroll
    for (int i = 0; i < 15; ++i) {
      float4 v = q[i];
      g = decay * (g + v.x); Slds[4 * i + 1][k] = (__bf16)(beta * g);
      g = decay * (g + v.y); Slds[4 * i + 2][k] = (__bf16)(beta * g);
      g = decay * (g + v.z); Slds[4 * i + 3][k] = (__bf16)(beta * g);
      g = decay * (g + v.w); Slds[4 * i + 4][k] = (__bf16)(beta * g);
    }
    {  // tail: obs t0+60..62 -> S[61..63]
      float4 v = q[15];
      g = decay * (g + v.x); Slds[61][k] = (__bf16)(beta * g);
      g = decay * (g + v.y); Slds[62][k] = (__bf16)(beta * g);
      g = decay * (g + v.z); Slds[63][k] = (__bf16)(beta * g);
    }
  }
  __syncthreads();

  // ---- MFMA GEMM: wave w covers j in [64w, 64w+64), all 64 t ----
  const int wave = tid >> 6;
  const int lane = tid & 63;
  const int lquad = lane >> 4;  // 0..3 -> k-octet within K=32 step / j-sub in C
  const int l16 = lane & 15;

  f32x4 acc[4][4];  // [jsub][tsub]
#pragma unroll
  for (int a = 0; a < 4; ++a)
#pragma unroll
    for (int b = 0; b < 4; ++b) acc[a][b] = (f32x4){0.f, 0.f, 0.f, 0.f};

  const __bf16* Abase = AlphaB + (size_t)(wave * 64 + l16) * KK + lquad * 8;
  for (int k0 = 0; k0 < KK; k0 += 32) {
    bf16x8 afrag[4], bfrag[4];
#pragma unroll
    for (int js = 0; js < 4; ++js)
      afrag[js] = *(const bf16x8*)(Abase + (size_t)js * 16 * KK + k0);
#pragma unroll
    for (int ts = 0; ts < 4; ++ts)
      bfrag[ts] = *(const bf16x8*)&Slds[ts * 16 + l16][k0 + lquad * 8];
#pragma unroll
    for (int js = 0; js < 4; ++js)
#pragma unroll
      for (int ts = 0; ts < 4; ++ts)
        acc[js][ts] = __builtin_amdgcn_mfma_f32_16x16x32_bf16(
            afrag[js], bfrag[ts], acc[js][ts], 0, 0, 0);
  }

  // ---- epilogue: softplus, lams0/lams1 stores, loglik partial ----
  // v0 layout: lanes 0..15 cover consecutive t -> each 16-lane group writes a
  // full 64B line per store; 4 rows per instruction. Best measured pattern.
  float partial = 0.f;
  float* lams0 = out + 1;
  float* lams1 = out + 1 + (size_t)KK * NN;
#pragma unroll
  for (int js = 0; js < 4; ++js) {
#pragma unroll
    for (int r = 0; r < 4; ++r) {
      const int j = wave * 64 + js * 16 + lquad * 4 + r;  // D row mapping
      const float m = mu0[j];
      const size_t rowoff = (size_t)j * NN + t0 + l16;
#pragma unroll
      for (int ts = 0; ts < 4; ++ts) {
        float v = acc[js][ts][r];                    // v >= 0 always
        float lam = v + __logf(1.f + __expf(-v));    // stable softplus
        if (t0 + ts * 16 + l16 == 0) lam = 0.f;      // lams1[:,0] = 0
        lams1[rowoff + ts * 16] = lam;
        lams0[rowoff + ts * 16] = m;
        const float o = obs[rowoff + ts * 16];
        partial += o * __logf(m + lam + 1e-5f) - m - lam;
      }
    }
  }

  // wave reduce, then block reduce through LDS (reused), NO atomics
#pragma unroll
  for (int off = 32; off > 0; off >>= 1)
    partial += __shfl_down(partial, off, 64);
  __syncthreads();                       // all waves done reading Slds
  float* red = (float*)&Slds[0][0];
  if (lane == 0) red[wave] = partial;
  __syncthreads();
  if (tid == 0) bpart[bid] = (red[0] + red[1]) + (red[2] + red[3]);
}

// ---------------------------------------------------------------------------
// Kernel 3: sum 1024 per-block partials -> out[0]. One block.
// ---------------------------------------------------------------------------
__global__ __launch_bounds__(256) void finish_kernel(const float* __restrict__ bpart,
                                                     float* __restrict__ out) {
  const int tid = threadIdx.x;
  f32x4 v = ((const f32x4*)bpart)[tid];
  float s = (v[0] + v[1]) + (v[2] + v[3]);
#pragma unroll
  for (int off = 32; off > 0; off >>= 1)
    s += __shfl_down(s, off, 64);
  __shared__ float red[4];
  if ((tid & 63) == 0) red[tid >> 6] = s;
  __syncthreads();
  if (tid == 0) out[0] = (red[0] + red[1]) + (red[2] + red[3]);
}

// ---------------------------------------------------------------------------
extern "C" void kernel_launch(void* const* d_in, const int* in_sizes, int n_in,
                              void* d_out, int out_size, void* d_ws, size_t ws_size,
                              hipStream_t stream) {
  const float* obs   = (const float*)d_in[0];
  const float* Beta  = (const float*)d_in[1];
  const float* Alpha = (const float*)d_in[2];
  float* out = (float*)d_out;

  float* mu0 = (float*)d_ws;                // 256 floats
  __bf16* AlphaB = (__bf16*)(mu0 + 256);    // 65536 bf16 = 32768 floats
  float* bpart = (float*)(AlphaB + (size_t)KK * KK);  // 1024 floats

  hipLaunchKernelGGL(prep_kernel, dim3(KK), dim3(256), 0, stream, obs, Alpha,
                     mu0, AlphaB);
  hipLaunchKernelGGL(main_kernel, dim3(NN / TT), dim3(256), 0, stream,
                     obs, Beta, mu0, AlphaB, out, bpart);
  hipLaunchKernelGGL(finish_kernel, dim3(1), dim3(256), 0, stream, bpart, out);
}

// Round 3
// 231.060 us; speedup vs baseline: 1.2496x; 1.0546x over previous
//
#include <hip/hip_runtime.h>
#include <math.h>

#define KK 256
#define NN 65536
#define TT 128   // time-tile columns per block (512B burst per row-visit)
#define WW 16    // scan lookback; decay<=e^-1 -> tail rel err ~e^-16=1e-7 << bf16 eps
#define TPAD 264 // 256 + 8 bf16 pad: breaks 512B-stride bank aliasing, keeps 16B align

typedef __bf16 bf16x8 __attribute__((ext_vector_type(8)));
typedef float f32x4 __attribute__((ext_vector_type(4)));

// ---------------------------------------------------------------------------
// Kernel 1: fused row-mean + mu0 + Alpha->bf16 + STREAMING lams0 fill.
//   Block j owns obs row j. lams0[j,:] = mu0[j] is GEMM-independent, so it is
//   written here as a full-row linear stream (vs 256B scatters in main).
// ---------------------------------------------------------------------------
__global__ __launch_bounds__(512) void prep_kernel(const float* __restrict__ obs,
                                                   const float* __restrict__ Alpha,
                                                   float* __restrict__ mu0,
                                                   __bf16* __restrict__ AlphaB,
                                                   float* __restrict__ out) {
  const int j = blockIdx.x;
  const int tid = threadIdx.x;
  if (tid < KK) AlphaB[(size_t)j * KK + tid] = (__bf16)Alpha[(size_t)j * KK + tid];
  const float4* p = (const float4*)(obs + (size_t)j * NN) + tid;
  float s = 0.f;
#pragma unroll
  for (int i = 0; i < 32; ++i) {
    float4 v = p[i * 512];
    s += (v.x + v.y) + (v.z + v.w);
  }
  __shared__ float red[512];
  red[tid] = s;
  __syncthreads();
  for (int off = 256; off > 0; off >>= 1) {
    if (tid < off) red[tid] += red[tid + off];
    __syncthreads();
  }
  const float m = red[0] * (1.0f / NN) * 0.1f + 0.01f;
  if (tid == 0) mu0[j] = m;

  // lams0 row fill: base out+1 is 4B-misaligned; peel t=0..2 and t=NN-1,
  // stream the rest as aligned float4.
  float* row0 = out + 1 + (size_t)j * NN;
  if (tid < 3) row0[tid] = m;
  if (tid == 3) row0[NN - 1] = m;
  float4* p4 = (float4*)(row0 + 3);  // 16B-aligned
  const float4 mv = {m, m, m, m};
  for (int i = tid; i < (NN - 4) / 4; i += 512) p4[i] = mv;
}

// ---------------------------------------------------------------------------
// Kernel 2: fused windowed-scan + bf16-MFMA GEMM + softplus + lams1 + loglik.
//   512 threads: scan threads (k, half) each produce 64 cols (WW lookback
//   makes chunks self-starting). 8 waves: wave (wj=w&3, wc=w>>2) computes
//   j in [64wj,64wj+64) x t in [t0+64wc, t0+64wc+64).
//   XCD swizzle keeps each XCD on a contiguous 8192-col span.
// ---------------------------------------------------------------------------
__global__ __launch_bounds__(512, 4) void main_kernel(const float* __restrict__ obs,
                                                      const float* __restrict__ Beta,
                                                      const float* __restrict__ mu0,
                                                      const __bf16* __restrict__ AlphaB,
                                                      float* __restrict__ out,
                                                      float* __restrict__ bpart) {
  __shared__ __bf16 Slds[TT][TPAD];  // 67.6 KB -> 2 blocks/CU
  const int tid = threadIdx.x;
  const int bid = blockIdx.x;
  const int tb = ((bid & 7) << 6) | (bid >> 3);  // bijective: 512 blocks, 64/XCD
  const int t0 = tb * TT;

  // ---- scan: thread (k = tid&255, c = tid>>8) -> S[k, t0+64c .. +63] ----
  {
    const int k = tid & 255;
    const int c = tid >> 8;
    const int tbase = t0 + 64 * c;
    const float beta = Beta[k];
    const float decay = expf(-beta);
    const float* row = obs + (size_t)k * NN;
    float g = 0.f;  // ~ H[k, tbase]; tail rel err < e^-16
    if (tbase > 0) {
      const float4* p = (const float4*)(row + tbase - WW);
#pragma unroll
      for (int i = 0; i < WW / 4; ++i) {
        float4 v = p[i];
        g = decay * (g + v.x);
        g = decay * (g + v.y);
        g = decay * (g + v.z);
        g = decay * (g + v.w);
      }
    }
    const int r0 = 64 * c;
    Slds[r0][k] = (__bf16)(beta * g);
    const float4* q = (const float4*)(row + tbase);
#pragma unroll
    for (int i = 0; i < 15; ++i) {
      float4 v = q[i];
      g = decay * (g + v.x); Slds[r0 + 4 * i + 1][k] = (__bf16)(beta * g);
      g = decay * (g + v.y); Slds[r0 + 4 * i + 2][k] = (__bf16)(beta * g);
      g = decay * (g + v.z); Slds[r0 + 4 * i + 3][k] = (__bf16)(beta * g);
      g = decay * (g + v.w); Slds[r0 + 4 * i + 4][k] = (__bf16)(beta * g);
    }
    {  // tail: obs tbase+60..62 -> S rows r0+61..63
      float4 v = q[15];
      g = decay * (g + v.x); Slds[r0 + 61][k] = (__bf16)(beta * g);
      g = decay * (g + v.y); Slds[r0 + 62][k] = (__bf16)(beta * g);
      g = decay * (g + v.z); Slds[r0 + 63][k] = (__bf16)(beta * g);
    }
  }
  __syncthreads();

  // ---- MFMA GEMM ----
  const int wave = tid >> 6;
  const int wj = wave & 3, wc = wave >> 2;
  const int lane = tid & 63;
  const int lquad = lane >> 4;  // k-octet within K=32 step / j-sub in C
  const int l16 = lane & 15;

  f32x4 acc[4][4];  // [jsub][tsub]
#pragma unroll
  for (int a = 0; a < 4; ++a)
#pragma unroll
    for (int b = 0; b < 4; ++b) acc[a][b] = (f32x4){0.f, 0.f, 0.f, 0.f};

  const __bf16* Abase = AlphaB + (size_t)(wj * 64 + l16) * KK + lquad * 8;
  for (int k0 = 0; k0 < KK; k0 += 32) {
    bf16x8 afrag[4], bfrag[4];
#pragma unroll
    for (int js = 0; js < 4; ++js)
      afrag[js] = *(const bf16x8*)(Abase + (size_t)js * 16 * KK + k0);
#pragma unroll
    for (int ts = 0; ts < 4; ++ts)
      bfrag[ts] = *(const bf16x8*)&Slds[wc * 64 + ts * 16 + l16][k0 + lquad * 8];
#pragma unroll
    for (int js = 0; js < 4; ++js)
#pragma unroll
      for (int ts = 0; ts < 4; ++ts)
        acc[js][ts] = __builtin_amdgcn_mfma_f32_16x16x32_bf16(
            afrag[js], bfrag[ts], acc[js][ts], 0, 0, 0);
  }

  // ---- epilogue: softplus, lams1 stores (coalesced 64B lines), loglik ----
  float partial = 0.f;
  float* lams1 = out + 1 + (size_t)KK * NN;
  const int tcol = t0 + wc * 64;
#pragma unroll
  for (int js = 0; js < 4; ++js) {
#pragma unroll
    for (int r = 0; r < 4; ++r) {
      const int j = wj * 64 + js * 16 + lquad * 4 + r;  // D row mapping
      const float m = mu0[j];
      const size_t rowoff = (size_t)j * NN + tcol + l16;
#pragma unroll
      for (int ts = 0; ts < 4; ++ts) {
        float v = acc[js][ts][r];                    // v >= 0 always
        float lam = v + __logf(1.f + __expf(-v));    // stable softplus
        if (tcol + ts * 16 + l16 == 0) lam = 0.f;    // lams1[:,0] = 0
        lams1[rowoff + ts * 16] = lam;
        const float o = obs[rowoff + ts * 16];
        partial += o * __logf(m + lam + 1e-5f) - m - lam;
      }
    }
  }

  // wave reduce, then block reduce through LDS (reused), no atomics
#pragma unroll
  for (int off = 32; off > 0; off >>= 1)
    partial += __shfl_down(partial, off, 64);
  __syncthreads();  // all waves done reading Slds
  float* red = (float*)&Slds[0][0];
  if (lane == 0) red[wave] = partial;
  __syncthreads();
  if (tid == 0) {
    float s = 0.f;
#pragma unroll
    for (int w = 0; w < 8; ++w) s += red[w];
    bpart[bid] = s;
  }
}

// ---------------------------------------------------------------------------
// Kernel 3: sum 512 per-block partials -> out[0]. One block.
// ---------------------------------------------------------------------------
__global__ __launch_bounds__(256) void finish_kernel(const float* __restrict__ bpart,
                                                     float* __restrict__ out) {
  const int tid = threadIdx.x;
  float s = bpart[tid] + bpart[tid + 256];
#pragma unroll
  for (int off = 32; off > 0; off >>= 1)
    s += __shfl_down(s, off, 64);
  __shared__ float red[4];
  if ((tid & 63) == 0) red[tid >> 6] = s;
  __syncthreads();
  if (tid == 0) out[0] = (red[0] + red[1]) + (red[2] + red[3]);
}

// ---------------------------------------------------------------------------
extern "C" void kernel_launch(void* const* d_in, const int* in_sizes, int n_in,
                              void* d_out, int out_size, void* d_ws, size_t ws_size,
                              hipStream_t stream) {
  const float* obs   = (const float*)d_in[0];
  const float* Beta  = (const float*)d_in[1];
  const float* Alpha = (const float*)d_in[2];
  float* out = (float*)d_out;

  float* mu0 = (float*)d_ws;                // 256 floats
  __bf16* AlphaB = (__bf16*)(mu0 + 256);    // 65536 bf16 = 32768 floats
  float* bpart = (float*)(AlphaB + (size_t)KK * KK);  // 512 floats

  hipLaunchKernelGGL(prep_kernel, dim3(KK), dim3(512), 0, stream, obs, Alpha,
                     mu0, AlphaB, out);
  hipLaunchKernelGGL(main_kernel, dim3(NN / TT), dim3(512), 0, stream,
                     obs, Beta, mu0, AlphaB, out, bpart);
  hipLaunchKernelGGL(finish_kernel, dim3(1), dim3(256), 0, stream, bpart, out);
}